// Round 1
// baseline (882.752 us; speedup 1.0000x reference)
//
#include <hip/hip_runtime.h>

#define NCH 128

static inline size_t align256(size_t x){ return (x + 255) & ~(size_t)255; }

// ---------------- CSR build ----------------

__global__ void hist_kernel(const int* __restrict__ col, int* __restrict__ counts, int E){
  int e = blockIdx.x * blockDim.x + threadIdx.x;
  if (e < E) atomicAdd(&counts[col[e]], 1);
}

__global__ void dinv_kernel(const int* __restrict__ counts, float* __restrict__ dinv, int N){
  int i = blockIdx.x * blockDim.x + threadIdx.x;
  if (i < N) dinv[i] = rsqrtf((float)counts[i] + 1.0f);  // +1 = self loop
}

__global__ void scan1_kernel(const int* __restrict__ counts, int* __restrict__ offs,
                             int* __restrict__ bsums, int n){
  __shared__ int sh[256];
  int t = threadIdx.x;
  int base = blockIdx.x * 1024 + t * 4;
  int v0 = (base + 0 < n) ? counts[base + 0] : 0;
  int v1 = (base + 1 < n) ? counts[base + 1] : 0;
  int v2 = (base + 2 < n) ? counts[base + 2] : 0;
  int v3 = (base + 3 < n) ? counts[base + 3] : 0;
  int tsum = v0 + v1 + v2 + v3;
  sh[t] = tsum; __syncthreads();
  for (int off = 1; off < 256; off <<= 1){
    int val = (t >= off) ? sh[t - off] : 0;
    __syncthreads();
    sh[t] += val;
    __syncthreads();
  }
  int ex = sh[t] - tsum;                 // exclusive prefix within block
  if (t == 255) bsums[blockIdx.x] = sh[255];
  if (base + 0 < n) offs[base + 0] = ex;
  if (base + 1 < n) offs[base + 1] = ex + v0;
  if (base + 2 < n) offs[base + 2] = ex + v0 + v1;
  if (base + 3 < n) offs[base + 3] = ex + v0 + v1 + v2;
}

__global__ void scan2_kernel(int* __restrict__ bsums, int nb){
  __shared__ int sh[256];
  int t = threadIdx.x;
  int v = (t < nb) ? bsums[t] : 0;
  sh[t] = v; __syncthreads();
  for (int off = 1; off < 256; off <<= 1){
    int val = (t >= off) ? sh[t - off] : 0;
    __syncthreads();
    sh[t] += val;
    __syncthreads();
  }
  if (t < nb) bsums[t] = sh[t] - v;      // exclusive
}

__global__ void scan3_kernel(int* __restrict__ offs, const int* __restrict__ bsums, int n){
  int base = blockIdx.x * 1024 + threadIdx.x * 4;
  int add = bsums[blockIdx.x];
  if (base + 0 < n) offs[base + 0] += add;
  if (base + 1 < n) offs[base + 1] += add;
  if (base + 2 < n) offs[base + 2] += add;
  if (base + 3 < n) offs[base + 3] += add;
}

__global__ void fill_kernel(const int* __restrict__ row, const int* __restrict__ col,
                            const int* __restrict__ offs, int* __restrict__ cursor,
                            int* __restrict__ rows_sorted, int E){
  int e = blockIdx.x * blockDim.x + threadIdx.x;
  if (e < E){
    int c = col[e];
    int pos = offs[c] + atomicAdd(&cursor[c], 1);
    rows_sorted[pos] = row[e];
  }
}

// ---------------- GEMM: [nrows,128] @ [128,128] fp32 ----------------
// 128-row tile per block, 256 threads, 8x8 register blocking.
__global__ __launch_bounds__(256) void gemm_128(
    const float* __restrict__ X, const float* __restrict__ W,
    float* __restrict__ O, int nrows){
  __shared__ float Ws[32 * 128];   // 16KB: W[k0..k0+31][0..127]
  __shared__ float Xs[128 * 32];   // 16KB: X[r][k0..k0+31]
  int t  = threadIdx.x;
  int tx = t & 15;    // column group: cols tx*4..tx*4+3 and 64+tx*4..
  int ty = t >> 4;    // row group: rows ty*8..ty*8+7
  int row0 = blockIdx.x * 128;

  float acc[8][8];
  #pragma unroll
  for (int i = 0; i < 8; i++)
    #pragma unroll
    for (int j = 0; j < 8; j++) acc[i][j] = 0.f;

  for (int kc = 0; kc < 4; kc++){
    int k0 = kc * 32;
    __syncthreads();
    // stage W chunk: 32x128 floats = 1024 float4, 4 per thread (coalesced)
    {
      const float4* Wg = (const float4*)(W + k0 * 128);
      float4* Wl = (float4*)Ws;
      #pragma unroll
      for (int q = 0; q < 4; q++) Wl[t + 256 * q] = Wg[t + 256 * q];
    }
    // stage X chunk: rows row0..row0+127, cols k0..k0+31
    {
      #pragma unroll
      for (int q = 0; q < 4; q++){
        int idx = t + 256 * q;      // float4 index 0..1023
        int r   = idx >> 3;         // 0..127
        int kq  = idx & 7;          // 0..7
        int gr  = row0 + r;
        int grc = (gr < nrows) ? gr : 0;
        float4 v = *(const float4*)(X + (size_t)grc * NCH + k0 + kq * 4);
        *(float4*)(Xs + r * 32 + kq * 4) = v;
      }
    }
    __syncthreads();
    #pragma unroll
    for (int k4 = 0; k4 < 8; k4++){
      float4 xv[8];
      #pragma unroll
      for (int i = 0; i < 8; i++)
        xv[i] = *(const float4*)(Xs + (ty * 8 + i) * 32 + k4 * 4);
      #pragma unroll
      for (int kk = 0; kk < 4; kk++){
        float4 w0 = *(const float4*)(Ws + (k4 * 4 + kk) * 128 + tx * 4);
        float4 w1 = *(const float4*)(Ws + (k4 * 4 + kk) * 128 + 64 + tx * 4);
        #pragma unroll
        for (int i = 0; i < 8; i++){
          float xs = (kk == 0) ? xv[i].x : (kk == 1) ? xv[i].y : (kk == 2) ? xv[i].z : xv[i].w;
          acc[i][0] += xs * w0.x; acc[i][1] += xs * w0.y;
          acc[i][2] += xs * w0.z; acc[i][3] += xs * w0.w;
          acc[i][4] += xs * w1.x; acc[i][5] += xs * w1.y;
          acc[i][6] += xs * w1.z; acc[i][7] += xs * w1.w;
        }
      }
    }
  }
  #pragma unroll
  for (int i = 0; i < 8; i++){
    int gr = row0 + ty * 8 + i;
    if (gr < nrows){
      float4 o0 = make_float4(acc[i][0], acc[i][1], acc[i][2], acc[i][3]);
      float4 o1 = make_float4(acc[i][4], acc[i][5], acc[i][6], acc[i][7]);
      *(float4*)(O + (size_t)gr * NCH + tx * 4)      = o0;
      *(float4*)(O + (size_t)gr * NCH + 64 + tx * 4) = o1;
    }
  }
}

// ---------------- GCN aggregation: one wave per node ----------------
// out[c] = maybe_relu( dinv[c] * ( dinv[c]*hp[c] + sum_e dinv[r_e]*hp[r_e] ) + bias )
__global__ __launch_bounds__(256) void agg_kernel(
    const float* __restrict__ hp, const float* __restrict__ dinv,
    const int* __restrict__ offs, const int* __restrict__ counts,
    const int* __restrict__ rows_sorted, const float* __restrict__ bias,
    float* __restrict__ outp, int N, int do_relu){
  int wave = (int)((blockIdx.x * blockDim.x + threadIdx.x) >> 6);
  int lane = threadIdx.x & 63;
  if (wave >= N) return;
  int c = wave;
  const float2* hp2 = (const float2*)hp;
  float di = dinv[c];
  float2 hc = hp2[(size_t)c * 64 + lane];
  float ax = di * hc.x;
  float ay = di * hc.y;
  int off = offs[c], cnt = counts[c];
  for (int e = 0; e < cnt; e++){
    int r = rows_sorted[off + e];
    float dr = dinv[r];
    float2 hr = hp2[(size_t)r * 64 + lane];
    ax += dr * hr.x;
    ay += dr * hr.y;
  }
  float2 bv = ((const float2*)bias)[lane];
  float ox = di * ax + bv.x;
  float oy = di * ay + bv.y;
  if (do_relu){ ox = fmaxf(ox, 0.f); oy = fmaxf(oy, 0.f); }
  ((float2*)outp)[(size_t)c * 64 + lane] = make_float2(ox, oy);
}

// ---------------- Pair head: wave per pair ----------------
// out[p] = dot(relu(A[src]+B[dst]+bm1), Wm2) + bm2
__global__ __launch_bounds__(256) void pair_kernel(
    const float* __restrict__ A, const float* __restrict__ B,
    const int* __restrict__ src, const int* __restrict__ dst,
    const float* __restrict__ bm1, const float* __restrict__ Wm2,
    const float* __restrict__ bm2, float* __restrict__ outp, int P){
  int gwave = (int)((blockIdx.x * blockDim.x + threadIdx.x) >> 6);
  int lane  = threadIdx.x & 63;
  int nw    = (int)((gridDim.x * blockDim.x) >> 6);
  const float2* A2 = (const float2*)A;
  const float2* B2 = (const float2*)B;
  float2 bb = ((const float2*)bm1)[lane];
  float2 ww = ((const float2*)Wm2)[lane];
  float bsc = bm2[0];
  for (int p = gwave; p < P; p += nw){
    int s = src[p], d = dst[p];
    float2 a = A2[(size_t)s * 64 + lane];
    float2 b = B2[(size_t)d * 64 + lane];
    float zx = fmaxf(a.x + b.x + bb.x, 0.f);
    float zy = fmaxf(a.y + b.y + bb.y, 0.f);
    float v  = zx * ww.x + zy * ww.y;
    #pragma unroll
    for (int off = 32; off > 0; off >>= 1) v += __shfl_down(v, off, 64);
    if (lane == 0) outp[p] = v + bsc;
  }
}

// ---------------- launch ----------------

extern "C" void kernel_launch(void* const* d_in, const int* in_sizes, int n_in,
                              void* d_out, int out_size, void* d_ws, size_t ws_size,
                              hipStream_t stream){
  const float* x   = (const float*)d_in[0];
  const int*   ei  = (const int*)  d_in[1];
  const int*   ep  = (const int*)  d_in[2];
  const float* W1  = (const float*)d_in[3];
  const float* b1  = (const float*)d_in[4];
  const float* W2  = (const float*)d_in[5];
  const float* b2  = (const float*)d_in[6];
  const float* Wm1 = (const float*)d_in[7];
  const float* bm1 = (const float*)d_in[8];
  const float* Wm2 = (const float*)d_in[9];
  const float* bm2 = (const float*)d_in[10];
  float* outp = (float*)d_out;

  const int N = in_sizes[0] / NCH;
  const int E = in_sizes[1] / 2;
  const int P = in_sizes[2] / 2;

  // workspace layout
  char* base = (char*)d_ws;
  size_t off = 0;
  int*   counts      = (int*)  (base + off); off = align256(off + (size_t)N * 4);
  int*   cursor      = (int*)  (base + off); off = align256(off + (size_t)N * 4);
  int*   offs        = (int*)  (base + off); off = align256(off + (size_t)N * 4);
  float* dinv        = (float*)(base + off); off = align256(off + (size_t)N * 4);
  int*   bsums       = (int*)  (base + off); off = align256(off + 4096);
  int*   rows_sorted = (int*)  (base + off); off = align256(off + (size_t)E * 4);
  float* buf0        = (float*)(base + off); off = align256(off + (size_t)N * NCH * 4);
  float* buf1        = (float*)(base + off); off = align256(off + (size_t)N * NCH * 4);
  float* buf2        = (float*)(base + off); off = align256(off + (size_t)N * NCH * 4);
  (void)ws_size; (void)n_in; (void)out_size;

  const int* row = ei;         // edge_index[0] = source
  const int* col = ei + E;     // edge_index[1] = target
  const int* psrc = ep;
  const int* pdst = ep + P;

  hipMemsetAsync(counts, 0, (size_t)N * 4, stream);
  hipMemsetAsync(cursor, 0, (size_t)N * 4, stream);

  int nb = (N + 1023) / 1024;
  hist_kernel <<<(E + 255) / 256, 256, 0, stream>>>(col, counts, E);
  dinv_kernel <<<(N + 255) / 256, 256, 0, stream>>>(counts, dinv, N);
  scan1_kernel<<<nb, 256, 0, stream>>>(counts, offs, bsums, N);
  scan2_kernel<<<1, 256, 0, stream>>>(bsums, nb);
  scan3_kernel<<<nb, 256, 0, stream>>>(offs, bsums, N);
  fill_kernel <<<(E + 255) / 256, 256, 0, stream>>>(row, col, offs, cursor, rows_sorted, E);

  int gemm_grid = (N + 127) / 128;
  int agg_grid  = (N + 3) / 4;

  // conv1: h1 = relu(agg(x@W1) + b1)
  gemm_128<<<gemm_grid, 256, 0, stream>>>(x, W1, buf0, N);
  agg_kernel<<<agg_grid, 256, 0, stream>>>(buf0, dinv, offs, counts, rows_sorted, b1, buf1, N, 1);
  // conv2: h2 = agg(h1@W2) + b2
  gemm_128<<<gemm_grid, 256, 0, stream>>>(buf1, W2, buf0, N);
  agg_kernel<<<agg_grid, 256, 0, stream>>>(buf0, dinv, offs, counts, rows_sorted, b2, buf1, N, 0);
  // pair head precompute: A = h2 @ Wm1[:128], B = h2 @ Wm1[128:]
  gemm_128<<<gemm_grid, 256, 0, stream>>>(buf1, Wm1, buf0, N);
  gemm_128<<<gemm_grid, 256, 0, stream>>>(buf1, Wm1 + 128 * 128, buf2, N);
  // out[p] = relu(A[src]+B[dst]+bm1) @ Wm2 + bm2
  pair_kernel<<<8192, 256, 0, stream>>>(buf0, buf2, psrc, pdst, bm1, Wm2, bm2, outp, P);
}

// Round 2
// 778.804 us; speedup vs baseline: 1.1335x; 1.1335x over previous
//
#include <hip/hip_runtime.h>

#define NCH 128

static inline size_t align256(size_t x){ return (x + 255) & ~(size_t)255; }

// ---------------- CSR build ----------------

__global__ void hist_kernel(const int* __restrict__ col, int* __restrict__ counts, int E){
  int e = blockIdx.x * blockDim.x + threadIdx.x;
  if (e < E) atomicAdd(&counts[col[e]], 1);
}

__global__ void dinv_kernel(const int* __restrict__ counts, float* __restrict__ dinv, int N){
  int i = blockIdx.x * blockDim.x + threadIdx.x;
  if (i < N) dinv[i] = rsqrtf((float)counts[i] + 1.0f);  // +1 = self loop
}

__global__ void scan1_kernel(const int* __restrict__ counts, int* __restrict__ offs,
                             int* __restrict__ bsums, int n){
  __shared__ int sh[256];
  int t = threadIdx.x;
  int base = blockIdx.x * 1024 + t * 4;
  int v0 = (base + 0 < n) ? counts[base + 0] : 0;
  int v1 = (base + 1 < n) ? counts[base + 1] : 0;
  int v2 = (base + 2 < n) ? counts[base + 2] : 0;
  int v3 = (base + 3 < n) ? counts[base + 3] : 0;
  int tsum = v0 + v1 + v2 + v3;
  sh[t] = tsum; __syncthreads();
  for (int off = 1; off < 256; off <<= 1){
    int val = (t >= off) ? sh[t - off] : 0;
    __syncthreads();
    sh[t] += val;
    __syncthreads();
  }
  int ex = sh[t] - tsum;                 // exclusive prefix within block
  if (t == 255) bsums[blockIdx.x] = sh[255];
  if (base + 0 < n) offs[base + 0] = ex;
  if (base + 1 < n) offs[base + 1] = ex + v0;
  if (base + 2 < n) offs[base + 2] = ex + v0 + v1;
  if (base + 3 < n) offs[base + 3] = ex + v0 + v1 + v2;
}

__global__ void scan2_kernel(int* __restrict__ bsums, int nb){
  __shared__ int sh[256];
  int t = threadIdx.x;
  int v = (t < nb) ? bsums[t] : 0;
  sh[t] = v; __syncthreads();
  for (int off = 1; off < 256; off <<= 1){
    int val = (t >= off) ? sh[t - off] : 0;
    __syncthreads();
    sh[t] += val;
    __syncthreads();
  }
  if (t < nb) bsums[t] = sh[t] - v;      // exclusive
}

__global__ void scan3_kernel(int* __restrict__ offs, const int* __restrict__ bsums, int n){
  int base = blockIdx.x * 1024 + threadIdx.x * 4;
  int add = bsums[blockIdx.x];
  if (base + 0 < n) offs[base + 0] += add;
  if (base + 1 < n) offs[base + 1] += add;
  if (base + 2 < n) offs[base + 2] += add;
  if (base + 3 < n) offs[base + 3] += add;
}

__global__ void fill_kernel(const int* __restrict__ row, const int* __restrict__ col,
                            const int* __restrict__ offs, int* __restrict__ cursor,
                            int* __restrict__ rows_sorted, int E){
  int e = blockIdx.x * blockDim.x + threadIdx.x;
  if (e < E){
    int c = col[e];
    int pos = offs[c] + atomicAdd(&cursor[c], 1);
    rows_sorted[pos] = row[e];
  }
}

// ---------------- GEMM: [nrows,128] @ [128,128] fp32 ----------------
// 128-row tile per block, 256 threads, 8x8 register blocking.
// Thread rows interleaved (ty + 16*i) and Xs padded to 36 floats/row so the
// 16 distinct ty addresses of each LDS b128 read spread across bank groups
// (2-way conflict = free) instead of 16-way on one group.
// Optional epilogue: scale output row by dinv[row] (fused GCN norm).
#define XS_STRIDE 36
__global__ __launch_bounds__(256) void gemm_128(
    const float* __restrict__ X, const float* __restrict__ W,
    const float* __restrict__ dinv, float* __restrict__ O,
    int nrows, int do_scale){
  __shared__ float Ws[32 * 128];          // 16 KB
  __shared__ float Xs[128 * XS_STRIDE];   // 18 KB
  int t  = threadIdx.x;
  int tx = t & 15;    // cols tx*4..tx*4+3 and 64+tx*4..
  int ty = t >> 4;    // rows ty + 16*i, i=0..7
  int row0 = blockIdx.x * 128;

  float acc[8][8];
  #pragma unroll
  for (int i = 0; i < 8; i++)
    #pragma unroll
    for (int j = 0; j < 8; j++) acc[i][j] = 0.f;

  for (int kc = 0; kc < 4; kc++){
    int k0 = kc * 32;
    __syncthreads();
    // stage W chunk: 32x128 floats = 1024 float4
    {
      const float4* Wg = (const float4*)(W + k0 * 128);
      float4* Wl = (float4*)Ws;
      #pragma unroll
      for (int q = 0; q < 4; q++) Wl[t + 256 * q] = Wg[t + 256 * q];
    }
    // stage X chunk: rows row0..row0+127, cols k0..k0+31 (padded stride)
    {
      #pragma unroll
      for (int q = 0; q < 4; q++){
        int idx = t + 256 * q;      // float4 index 0..1023
        int r   = idx >> 3;         // 0..127
        int kq  = idx & 7;          // 0..7
        int gr  = row0 + r;
        int grc = (gr < nrows) ? gr : 0;
        float4 v = *(const float4*)(X + (size_t)grc * NCH + k0 + kq * 4);
        *(float4*)(Xs + r * XS_STRIDE + kq * 4) = v;
      }
    }
    __syncthreads();
    #pragma unroll
    for (int k4 = 0; k4 < 8; k4++){
      float4 xv[8];
      #pragma unroll
      for (int i = 0; i < 8; i++)
        xv[i] = *(const float4*)(Xs + (ty + 16 * i) * XS_STRIDE + k4 * 4);
      #pragma unroll
      for (int kk = 0; kk < 4; kk++){
        float4 w0 = *(const float4*)(Ws + (k4 * 4 + kk) * 128 + tx * 4);
        float4 w1 = *(const float4*)(Ws + (k4 * 4 + kk) * 128 + 64 + tx * 4);
        #pragma unroll
        for (int i = 0; i < 8; i++){
          float xs = (kk == 0) ? xv[i].x : (kk == 1) ? xv[i].y : (kk == 2) ? xv[i].z : xv[i].w;
          acc[i][0] += xs * w0.x; acc[i][1] += xs * w0.y;
          acc[i][2] += xs * w0.z; acc[i][3] += xs * w0.w;
          acc[i][4] += xs * w1.x; acc[i][5] += xs * w1.y;
          acc[i][6] += xs * w1.z; acc[i][7] += xs * w1.w;
        }
      }
    }
  }
  #pragma unroll
  for (int i = 0; i < 8; i++){
    int gr = row0 + ty + 16 * i;
    if (gr < nrows){
      float sc = do_scale ? dinv[gr] : 1.0f;
      float4 o0 = make_float4(acc[i][0] * sc, acc[i][1] * sc, acc[i][2] * sc, acc[i][3] * sc);
      float4 o1 = make_float4(acc[i][4] * sc, acc[i][5] * sc, acc[i][6] * sc, acc[i][7] * sc);
      *(float4*)(O + (size_t)gr * NCH + tx * 4)      = o0;
      *(float4*)(O + (size_t)gr * NCH + 64 + tx * 4) = o1;
    }
  }
}

// ---------------- GCN aggregation: one wave per node ----------------
// s = dinv-scaled transformed features (dinv[r]*h[r], fused in GEMM epilogue)
// out[c] = maybe_relu( dinv[c] * ( s[c] + sum_e s[r_e] ) + bias )
// Cooperative index load (64/coalesced read) + 8-deep gather unroll for MLP.
__global__ __launch_bounds__(256) void agg_kernel(
    const float* __restrict__ s, const float* __restrict__ dinv,
    const int* __restrict__ offs, const int* __restrict__ counts,
    const int* __restrict__ rows_sorted, const float* __restrict__ bias,
    float* __restrict__ outp, int N, int do_relu){
  int wave = (int)((blockIdx.x * blockDim.x + threadIdx.x) >> 6);
  int lane = threadIdx.x & 63;
  if (wave >= N) return;
  int c = wave;
  const float2* s2 = (const float2*)s;
  float2 self = s2[(size_t)c * 64 + lane];
  float ax = self.x, ay = self.y;
  int off = offs[c], cnt = counts[c];
  for (int chunk = 0; chunk < cnt; chunk += 64){
    int nn = min(64, cnt - chunk);
    int myidx = (lane < nn) ? rows_sorted[off + chunk + lane] : 0;
    int e = 0;
    for (; e + 8 <= nn; e += 8){
      int r0 = __shfl(myidx, e + 0, 64);
      int r1 = __shfl(myidx, e + 1, 64);
      int r2 = __shfl(myidx, e + 2, 64);
      int r3 = __shfl(myidx, e + 3, 64);
      int r4 = __shfl(myidx, e + 4, 64);
      int r5 = __shfl(myidx, e + 5, 64);
      int r6 = __shfl(myidx, e + 6, 64);
      int r7 = __shfl(myidx, e + 7, 64);
      float2 v0 = s2[(size_t)r0 * 64 + lane];
      float2 v1 = s2[(size_t)r1 * 64 + lane];
      float2 v2 = s2[(size_t)r2 * 64 + lane];
      float2 v3 = s2[(size_t)r3 * 64 + lane];
      float2 v4 = s2[(size_t)r4 * 64 + lane];
      float2 v5 = s2[(size_t)r5 * 64 + lane];
      float2 v6 = s2[(size_t)r6 * 64 + lane];
      float2 v7 = s2[(size_t)r7 * 64 + lane];
      ax += v0.x + v1.x + v2.x + v3.x + v4.x + v5.x + v6.x + v7.x;
      ay += v0.y + v1.y + v2.y + v3.y + v4.y + v5.y + v6.y + v7.y;
    }
    for (; e < nn; e++){
      int r = __shfl(myidx, e, 64);
      float2 v = s2[(size_t)r * 64 + lane];
      ax += v.x; ay += v.y;
    }
  }
  float di = dinv[c];
  float2 bv = ((const float2*)bias)[lane];
  float ox = di * ax + bv.x;
  float oy = di * ay + bv.y;
  if (do_relu){ ox = fmaxf(ox, 0.f); oy = fmaxf(oy, 0.f); }
  ((float2*)outp)[(size_t)c * 64 + lane] = make_float2(ox, oy);
}

// ---------------- Pair head: wave per 2 pairs (4 gathers in flight) ----------------
// out[p] = dot(relu(A[src]+B[dst]+bm1), Wm2) + bm2
__global__ __launch_bounds__(256) void pair_kernel(
    const float* __restrict__ A, const float* __restrict__ B,
    const int* __restrict__ src, const int* __restrict__ dst,
    const float* __restrict__ bm1, const float* __restrict__ Wm2,
    const float* __restrict__ bm2, float* __restrict__ outp, int P){
  int gwave = (int)((blockIdx.x * blockDim.x + threadIdx.x) >> 6);
  int lane  = threadIdx.x & 63;
  int nw    = (int)((gridDim.x * blockDim.x) >> 6);
  const float2* A2 = (const float2*)A;
  const float2* B2 = (const float2*)B;
  float2 bb = ((const float2*)bm1)[lane];
  float2 ww = ((const float2*)Wm2)[lane];
  float bsc = bm2[0];
  for (int p = gwave * 2; p < P; p += nw * 2){
    int p1ok = (p + 1 < P);
    int s0 = src[p], d0 = dst[p];
    int s1 = p1ok ? src[p + 1] : s0;
    int d1 = p1ok ? dst[p + 1] : d0;
    float2 a0 = A2[(size_t)s0 * 64 + lane];
    float2 b0 = B2[(size_t)d0 * 64 + lane];
    float2 a1 = A2[(size_t)s1 * 64 + lane];
    float2 b1 = B2[(size_t)d1 * 64 + lane];
    float zx0 = fmaxf(a0.x + b0.x + bb.x, 0.f);
    float zy0 = fmaxf(a0.y + b0.y + bb.y, 0.f);
    float zx1 = fmaxf(a1.x + b1.x + bb.x, 0.f);
    float zy1 = fmaxf(a1.y + b1.y + bb.y, 0.f);
    float v0 = zx0 * ww.x + zy0 * ww.y;
    float v1 = zx1 * ww.x + zy1 * ww.y;
    #pragma unroll
    for (int off = 32; off > 0; off >>= 1){
      v0 += __shfl_down(v0, off, 64);
      v1 += __shfl_down(v1, off, 64);
    }
    if (lane == 0){
      outp[p] = v0 + bsc;
      if (p1ok) outp[p + 1] = v1 + bsc;
    }
  }
}

// ---------------- launch ----------------

extern "C" void kernel_launch(void* const* d_in, const int* in_sizes, int n_in,
                              void* d_out, int out_size, void* d_ws, size_t ws_size,
                              hipStream_t stream){
  const float* x   = (const float*)d_in[0];
  const int*   ei  = (const int*)  d_in[1];
  const int*   ep  = (const int*)  d_in[2];
  const float* W1  = (const float*)d_in[3];
  const float* b1  = (const float*)d_in[4];
  const float* W2  = (const float*)d_in[5];
  const float* b2  = (const float*)d_in[6];
  const float* Wm1 = (const float*)d_in[7];
  const float* bm1 = (const float*)d_in[8];
  const float* Wm2 = (const float*)d_in[9];
  const float* bm2 = (const float*)d_in[10];
  float* outp = (float*)d_out;

  const int N = in_sizes[0] / NCH;
  const int E = in_sizes[1] / 2;
  const int P = in_sizes[2] / 2;

  // workspace layout
  char* base = (char*)d_ws;
  size_t off = 0;
  int*   counts      = (int*)  (base + off); off = align256(off + (size_t)N * 4);
  int*   cursor      = (int*)  (base + off); off = align256(off + (size_t)N * 4);
  int*   offs        = (int*)  (base + off); off = align256(off + (size_t)N * 4);
  float* dinv        = (float*)(base + off); off = align256(off + (size_t)N * 4);
  int*   bsums       = (int*)  (base + off); off = align256(off + 4096);
  int*   rows_sorted = (int*)  (base + off); off = align256(off + (size_t)E * 4);
  float* buf0        = (float*)(base + off); off = align256(off + (size_t)N * NCH * 4);
  float* buf1        = (float*)(base + off); off = align256(off + (size_t)N * NCH * 4);
  float* buf2        = (float*)(base + off); off = align256(off + (size_t)N * NCH * 4);
  (void)ws_size; (void)n_in; (void)out_size;

  const int* row = ei;         // edge_index[0] = source
  const int* col = ei + E;     // edge_index[1] = target
  const int* psrc = ep;
  const int* pdst = ep + P;

  hipMemsetAsync(counts, 0, (size_t)N * 4, stream);
  hipMemsetAsync(cursor, 0, (size_t)N * 4, stream);

  int nb = (N + 1023) / 1024;
  hist_kernel <<<(E + 255) / 256, 256, 0, stream>>>(col, counts, E);
  dinv_kernel <<<(N + 255) / 256, 256, 0, stream>>>(counts, dinv, N);
  scan1_kernel<<<nb, 256, 0, stream>>>(counts, offs, bsums, N);
  scan2_kernel<<<1, 256, 0, stream>>>(bsums, nb);
  scan3_kernel<<<nb, 256, 0, stream>>>(offs, bsums, N);
  fill_kernel <<<(E + 255) / 256, 256, 0, stream>>>(row, col, offs, cursor, rows_sorted, E);

  int gemm_grid = (N + 127) / 128;
  int agg_grid  = (N + 3) / 4;

  // conv1: s1 = dinv * (x@W1);  h1 = relu(dinv*(s1[c] + sum s1[r]) + b1)
  gemm_128<<<gemm_grid, 256, 0, stream>>>(x, W1, dinv, buf0, N, 1);
  agg_kernel<<<agg_grid, 256, 0, stream>>>(buf0, dinv, offs, counts, rows_sorted, b1, buf1, N, 1);
  // conv2: s2 = dinv * (h1@W2); h2 = dinv*(s2[c] + sum s2[r]) + b2
  gemm_128<<<gemm_grid, 256, 0, stream>>>(buf1, W2, dinv, buf0, N, 1);
  agg_kernel<<<agg_grid, 256, 0, stream>>>(buf0, dinv, offs, counts, rows_sorted, b2, buf1, N, 0);
  // pair head precompute: A = h2 @ Wm1[:128], B = h2 @ Wm1[128:]
  gemm_128<<<gemm_grid, 256, 0, stream>>>(buf1, Wm1, dinv, buf0, N, 0);
  gemm_128<<<gemm_grid, 256, 0, stream>>>(buf1, Wm1 + 128 * 128, dinv, buf2, N, 0);
  // out[p] = relu(A[src]+B[dst]+bm1) @ Wm2 + bm2
  pair_kernel<<<8192, 256, 0, stream>>>(buf0, buf2, psrc, pdst, bm1, Wm2, bm2, outp, P);
}

// Round 3
// 617.324 us; speedup vs baseline: 1.4300x; 1.2616x over previous
//
#include <hip/hip_runtime.h>
#include <hip/hip_fp16.h>

#define NCH 128

typedef __attribute__((ext_vector_type(8))) short short8;
typedef __attribute__((ext_vector_type(4))) float floatx4;

static inline size_t align256(size_t x){ return (x + 255) & ~(size_t)255; }

// ---------------- CSR build ----------------

__global__ void hist_kernel(const int* __restrict__ col, int* __restrict__ counts, int E){
  int e = blockIdx.x * blockDim.x + threadIdx.x;
  if (e < E) atomicAdd(&counts[col[e]], 1);
}

__global__ void dinv_kernel(const int* __restrict__ counts, float* __restrict__ dinv, int N){
  int i = blockIdx.x * blockDim.x + threadIdx.x;
  if (i < N) dinv[i] = rsqrtf((float)counts[i] + 1.0f);  // +1 = self loop
}

__global__ void scan1_kernel(const int* __restrict__ counts, int* __restrict__ offs,
                             int* __restrict__ bsums, int n){
  __shared__ int sh[256];
  int t = threadIdx.x;
  int base = blockIdx.x * 1024 + t * 4;
  int v0 = (base + 0 < n) ? counts[base + 0] : 0;
  int v1 = (base + 1 < n) ? counts[base + 1] : 0;
  int v2 = (base + 2 < n) ? counts[base + 2] : 0;
  int v3 = (base + 3 < n) ? counts[base + 3] : 0;
  int tsum = v0 + v1 + v2 + v3;
  sh[t] = tsum; __syncthreads();
  for (int off = 1; off < 256; off <<= 1){
    int val = (t >= off) ? sh[t - off] : 0;
    __syncthreads();
    sh[t] += val;
    __syncthreads();
  }
  int ex = sh[t] - tsum;
  if (t == 255) bsums[blockIdx.x] = sh[255];
  if (base + 0 < n) offs[base + 0] = ex;
  if (base + 1 < n) offs[base + 1] = ex + v0;
  if (base + 2 < n) offs[base + 2] = ex + v0 + v1;
  if (base + 3 < n) offs[base + 3] = ex + v0 + v1 + v2;
}

__global__ void scan2_kernel(int* __restrict__ bsums, int nb){
  __shared__ int sh[256];
  int t = threadIdx.x;
  int v = (t < nb) ? bsums[t] : 0;
  sh[t] = v; __syncthreads();
  for (int off = 1; off < 256; off <<= 1){
    int val = (t >= off) ? sh[t - off] : 0;
    __syncthreads();
    sh[t] += val;
    __syncthreads();
  }
  if (t < nb) bsums[t] = sh[t] - v;
}

__global__ void scan3_kernel(int* __restrict__ offs, const int* __restrict__ bsums, int n){
  int base = blockIdx.x * 1024 + threadIdx.x * 4;
  int add = bsums[blockIdx.x];
  if (base + 0 < n) offs[base + 0] += add;
  if (base + 1 < n) offs[base + 1] += add;
  if (base + 2 < n) offs[base + 2] += add;
  if (base + 3 < n) offs[base + 3] += add;
}

__global__ void fill_kernel(const int* __restrict__ row, const int* __restrict__ col,
                            const int* __restrict__ offs, int* __restrict__ cursor,
                            int* __restrict__ rows_sorted, int E){
  int e = blockIdx.x * blockDim.x + threadIdx.x;
  if (e < E){
    int c = col[e];
    int pos = offs[c] + atomicAdd(&cursor[c], 1);
    rows_sorted[pos] = row[e];
  }
}

// ---------------- W split-transpose prep ----------------
// src: fp32 [128k][128n] row-major. dst: bf16 hi/lo planes [n][k] (k-contiguous),
// so GEMM B-fragments (need 8 consecutive k) are ds_read_b128-able.
__global__ void wsplit_kernel(const float* __restrict__ src,
                              short* __restrict__ dsthi, short* __restrict__ dstlo){
  int idx = blockIdx.x * blockDim.x + threadIdx.x;   // 0..16383
  int k = idx >> 7, n = idx & 127;
  float x = src[idx];
  unsigned u = __float_as_uint(x);
  short hs = (short)(u >> 16);                       // truncated bf16 hi
  float hf = __uint_as_float(u & 0xFFFF0000u);
  float lf = x - hf;                                 // exact residual
  short ls = (short)(__float_as_uint(lf) >> 16);     // bf16 lo
  dsthi[n * 128 + k] = hs;
  dstlo[n * 128 + k] = ls;
}

// ---------------- GEMM: [nrows,128] @ [128,128], split-bf16 MFMA ----------------
// C = X @ W computed as (Xhi+Xlo)@(Whi+Wlo) ~ Xhi@Whi + Xlo@Whi + Xhi@Wlo
// (rel err ~2^-16). X split on the fly during staging; W pre-split/transposed.
// 128x128 tile / block, 4 waves, each wave: 32 rows x 128 cols.
// K in 4 chunks of 32 (one 16x16x32 k-step per chunk).
// LDS row stride 40 shorts (80 B): 16-lane frag reads hit banks 20m%32 -> 2-way (free).
// Output fp16 (consumers are gather kernels), optional per-row dinv scale.
#define KST 40
__global__ __launch_bounds__(256, 2) void gemm_mfma(
    const float* __restrict__ X, const short* __restrict__ Wthi,
    const short* __restrict__ Wtlo, const float* __restrict__ scale,
    __half* __restrict__ O, int nrows, int do_scale){
  __shared__ short Xhi[128 * KST];
  __shared__ short Xlo[128 * KST];
  __shared__ short Whi[128 * KST];
  __shared__ short Wlo[128 * KST];
  int t = threadIdx.x;
  int w = t >> 6;            // wave 0..3 -> rows w*32..w*32+31
  int lane = t & 63;
  int m = lane & 15;         // frag row/col within 16
  int q = lane >> 4;         // quad -> k = q*8+j ; C row = q*4+reg
  int row0 = blockIdx.x * 128;

  floatx4 acc[2][8];
  #pragma unroll
  for (int rt = 0; rt < 2; rt++)
    #pragma unroll
    for (int ct = 0; ct < 8; ct++) acc[rt][ct] = (floatx4)0.f;

  for (int kc = 0; kc < 4; kc++){
    int k0 = kc * 32;
    __syncthreads();
    // stage X chunk (rows 0..127, k k0..k0+31) with hi/lo split
    #pragma unroll
    for (int qq = 0; qq < 4; qq++){
      int f = t + 256 * qq;        // float4 id 0..1023
      int r = f >> 3;              // 0..127
      int kq = f & 7;              // 0..7
      int gr = row0 + r;
      int grc = (gr < nrows) ? gr : 0;
      float4 v = *(const float4*)(X + (size_t)grc * NCH + k0 + kq * 4);
      short h[4], l[4];
      float vv[4] = {v.x, v.y, v.z, v.w};
      #pragma unroll
      for (int j = 0; j < 4; j++){
        unsigned u = __float_as_uint(vv[j]);
        h[j] = (short)(u >> 16);
        float hf = __uint_as_float(u & 0xFFFF0000u);
        l[j] = (short)(__float_as_uint(vv[j] - hf) >> 16);
      }
      *(uint2*)(Xhi + r * KST + kq * 4) = *(uint2*)h;
      *(uint2*)(Xlo + r * KST + kq * 4) = *(uint2*)l;
    }
    // stage W chunk (n 0..127, k k0..k0+31), straight copy of pre-split planes
    #pragma unroll
    for (int qq = 0; qq < 4; qq++){
      int u = t + 256 * qq;        // 4-short chunk id 0..1023
      int n = u >> 3, kq = u & 7;
      *(uint2*)(Whi + n * KST + kq * 4) = *(const uint2*)(Wthi + n * 128 + k0 + kq * 4);
      *(uint2*)(Wlo + n * KST + kq * 4) = *(const uint2*)(Wtlo + n * 128 + k0 + kq * 4);
    }
    __syncthreads();

    short8 a_hi0 = *(const short8*)(Xhi + (w * 32 + m) * KST + q * 8);
    short8 a_hi1 = *(const short8*)(Xhi + (w * 32 + 16 + m) * KST + q * 8);
    short8 a_lo0 = *(const short8*)(Xlo + (w * 32 + m) * KST + q * 8);
    short8 a_lo1 = *(const short8*)(Xlo + (w * 32 + 16 + m) * KST + q * 8);
    #pragma unroll
    for (int ct = 0; ct < 8; ct++){
      short8 b_hi = *(const short8*)(Whi + (ct * 16 + m) * KST + q * 8);
      short8 b_lo = *(const short8*)(Wlo + (ct * 16 + m) * KST + q * 8);
      acc[0][ct] = __builtin_amdgcn_mfma_f32_16x16x32_bf16(a_hi0, b_hi, acc[0][ct], 0, 0, 0);
      acc[0][ct] = __builtin_amdgcn_mfma_f32_16x16x32_bf16(a_lo0, b_hi, acc[0][ct], 0, 0, 0);
      acc[0][ct] = __builtin_amdgcn_mfma_f32_16x16x32_bf16(a_hi0, b_lo, acc[0][ct], 0, 0, 0);
      acc[1][ct] = __builtin_amdgcn_mfma_f32_16x16x32_bf16(a_hi1, b_hi, acc[1][ct], 0, 0, 0);
      acc[1][ct] = __builtin_amdgcn_mfma_f32_16x16x32_bf16(a_lo1, b_hi, acc[1][ct], 0, 0, 0);
      acc[1][ct] = __builtin_amdgcn_mfma_f32_16x16x32_bf16(a_hi1, b_lo, acc[1][ct], 0, 0, 0);
    }
  }
  // epilogue: C[row][col], row = w*32+rt*16+q*4+reg, col = ct*16+m
  #pragma unroll
  for (int rt = 0; rt < 2; rt++){
    #pragma unroll
    for (int r = 0; r < 4; r++){
      int grow = row0 + w * 32 + rt * 16 + q * 4 + r;
      if (grow < nrows){
        float sc = do_scale ? scale[grow] : 1.0f;
        #pragma unroll
        for (int ct = 0; ct < 8; ct++){
          int gcol = ct * 16 + m;
          O[(size_t)grow * NCH + gcol] = __float2half(acc[rt][ct][r] * sc);
        }
      }
    }
  }
}

// ---------------- GCN aggregation: one wave per node, fp16 gathers ----------------
// s = fp16 dinv-scaled transformed features.
// out[c] = maybe_relu( dinv[c] * ( s[c] + sum_e s[r_e] ) + bias ), fp32 out.
__global__ __launch_bounds__(256) void agg_kernel(
    const __half2* __restrict__ s2, const float* __restrict__ dinv,
    const int* __restrict__ offs, const int* __restrict__ counts,
    const int* __restrict__ rows_sorted, const float* __restrict__ bias,
    float* __restrict__ outp, int N, int do_relu){
  int wave = (int)((blockIdx.x * blockDim.x + threadIdx.x) >> 6);
  int lane = threadIdx.x & 63;
  if (wave >= N) return;
  int c = wave;
  float2 self = __half22float2(s2[(size_t)c * 64 + lane]);
  float ax = self.x, ay = self.y;
  int off = offs[c], cnt = counts[c];
  for (int chunk = 0; chunk < cnt; chunk += 64){
    int nn = min(64, cnt - chunk);
    int myidx = (lane < nn) ? rows_sorted[off + chunk + lane] : 0;
    int e = 0;
    for (; e + 8 <= nn; e += 8){
      int r0 = __shfl(myidx, e + 0, 64);
      int r1 = __shfl(myidx, e + 1, 64);
      int r2 = __shfl(myidx, e + 2, 64);
      int r3 = __shfl(myidx, e + 3, 64);
      int r4 = __shfl(myidx, e + 4, 64);
      int r5 = __shfl(myidx, e + 5, 64);
      int r6 = __shfl(myidx, e + 6, 64);
      int r7 = __shfl(myidx, e + 7, 64);
      __half2 v0 = s2[(size_t)r0 * 64 + lane];
      __half2 v1 = s2[(size_t)r1 * 64 + lane];
      __half2 v2 = s2[(size_t)r2 * 64 + lane];
      __half2 v3 = s2[(size_t)r3 * 64 + lane];
      __half2 v4 = s2[(size_t)r4 * 64 + lane];
      __half2 v5 = s2[(size_t)r5 * 64 + lane];
      __half2 v6 = s2[(size_t)r6 * 64 + lane];
      __half2 v7 = s2[(size_t)r7 * 64 + lane];
      float2 f0 = __half22float2(v0), f1 = __half22float2(v1);
      float2 f2 = __half22float2(v2), f3 = __half22float2(v3);
      float2 f4 = __half22float2(v4), f5 = __half22float2(v5);
      float2 f6 = __half22float2(v6), f7 = __half22float2(v7);
      ax += f0.x + f1.x + f2.x + f3.x + f4.x + f5.x + f6.x + f7.x;
      ay += f0.y + f1.y + f2.y + f3.y + f4.y + f5.y + f6.y + f7.y;
    }
    for (; e < nn; e++){
      int r = __shfl(myidx, e, 64);
      float2 f = __half22float2(s2[(size_t)r * 64 + lane]);
      ax += f.x; ay += f.y;
    }
  }
  float di = dinv[c];
  float2 bv = ((const float2*)bias)[lane];
  float ox = di * ax + bv.x;
  float oy = di * ay + bv.y;
  if (do_relu){ ox = fmaxf(ox, 0.f); oy = fmaxf(oy, 0.f); }
  ((float2*)outp)[(size_t)c * 64 + lane] = make_float2(ox, oy);
}

// ---------------- Pair head: wave per 2 pairs, fp16 gathers ----------------
__global__ __launch_bounds__(256) void pair_kernel(
    const __half2* __restrict__ A2, const __half2* __restrict__ B2,
    const int* __restrict__ src, const int* __restrict__ dst,
    const float* __restrict__ bm1, const float* __restrict__ Wm2,
    const float* __restrict__ bm2, float* __restrict__ outp, int P){
  int gwave = (int)((blockIdx.x * blockDim.x + threadIdx.x) >> 6);
  int lane  = threadIdx.x & 63;
  int nw    = (int)((gridDim.x * blockDim.x) >> 6);
  float2 bb = ((const float2*)bm1)[lane];
  float2 ww = ((const float2*)Wm2)[lane];
  float bsc = bm2[0];
  for (int p = gwave * 2; p < P; p += nw * 2){
    int p1ok = (p + 1 < P);
    int s0 = src[p], d0 = dst[p];
    int s1 = p1ok ? src[p + 1] : s0;
    int d1 = p1ok ? dst[p + 1] : d0;
    float2 a0 = __half22float2(A2[(size_t)s0 * 64 + lane]);
    float2 b0 = __half22float2(B2[(size_t)d0 * 64 + lane]);
    float2 a1 = __half22float2(A2[(size_t)s1 * 64 + lane]);
    float2 b1 = __half22float2(B2[(size_t)d1 * 64 + lane]);
    float zx0 = fmaxf(a0.x + b0.x + bb.x, 0.f);
    float zy0 = fmaxf(a0.y + b0.y + bb.y, 0.f);
    float zx1 = fmaxf(a1.x + b1.x + bb.x, 0.f);
    float zy1 = fmaxf(a1.y + b1.y + bb.y, 0.f);
    float v0 = zx0 * ww.x + zy0 * ww.y;
    float v1 = zx1 * ww.x + zy1 * ww.y;
    #pragma unroll
    for (int off = 32; off > 0; off >>= 1){
      v0 += __shfl_down(v0, off, 64);
      v1 += __shfl_down(v1, off, 64);
    }
    if (lane == 0){
      outp[p] = v0 + bsc;
      if (p1ok) outp[p + 1] = v1 + bsc;
    }
  }
}

// ---------------- launch ----------------

extern "C" void kernel_launch(void* const* d_in, const int* in_sizes, int n_in,
                              void* d_out, int out_size, void* d_ws, size_t ws_size,
                              hipStream_t stream){
  const float* x   = (const float*)d_in[0];
  const int*   ei  = (const int*)  d_in[1];
  const int*   ep  = (const int*)  d_in[2];
  const float* W1  = (const float*)d_in[3];
  const float* b1  = (const float*)d_in[4];
  const float* W2  = (const float*)d_in[5];
  const float* b2  = (const float*)d_in[6];
  const float* Wm1 = (const float*)d_in[7];
  const float* bm1 = (const float*)d_in[8];
  const float* Wm2 = (const float*)d_in[9];
  const float* bm2 = (const float*)d_in[10];
  float* outp = (float*)d_out;

  const int N = in_sizes[0] / NCH;
  const int E = in_sizes[1] / 2;
  const int P = in_sizes[2] / 2;

  // workspace layout
  char* base = (char*)d_ws;
  size_t off = 0;
  int*   counts      = (int*)  (base + off); off = align256(off + (size_t)N * 4);
  int*   cursor      = (int*)  (base + off); off = align256(off + (size_t)N * 4);
  int*   offs        = (int*)  (base + off); off = align256(off + (size_t)N * 4);
  float* dinv        = (float*)(base + off); off = align256(off + (size_t)N * 4);
  int*   bsums       = (int*)  (base + off); off = align256(off + 4096);
  int*   rows_sorted = (int*)  (base + off); off = align256(off + (size_t)E * 4);
  short* wt_planes   = (short*)(base + off); off = align256(off + (size_t)8 * 128 * 128 * 2);
  float* hbuf        = (float*)(base + off); off = align256(off + (size_t)N * NCH * 4);
  __half* sA         = (__half*)(base + off); off = align256(off + (size_t)N * NCH * 2);
  __half* sB         = (__half*)(base + off); off = align256(off + (size_t)N * NCH * 2);
  (void)ws_size; (void)n_in; (void)out_size;

  short* W1hi  = wt_planes + 0 * 16384;
  short* W1lo  = wt_planes + 1 * 16384;
  short* W2hi  = wt_planes + 2 * 16384;
  short* W2lo  = wt_planes + 3 * 16384;
  short* Wm1ahi= wt_planes + 4 * 16384;
  short* Wm1alo= wt_planes + 5 * 16384;
  short* Wm1bhi= wt_planes + 6 * 16384;
  short* Wm1blo= wt_planes + 7 * 16384;

  const int* row = ei;         // edge_index[0] = source
  const int* col = ei + E;     // edge_index[1] = target
  const int* psrc = ep;
  const int* pdst = ep + P;

  hipMemsetAsync(counts, 0, (size_t)N * 4, stream);
  hipMemsetAsync(cursor, 0, (size_t)N * 4, stream);

  int nb = (N + 1023) / 1024;
  hist_kernel <<<(E + 255) / 256, 256, 0, stream>>>(col, counts, E);
  dinv_kernel <<<(N + 255) / 256, 256, 0, stream>>>(counts, dinv, N);
  scan1_kernel<<<nb, 256, 0, stream>>>(counts, offs, bsums, N);
  scan2_kernel<<<1, 256, 0, stream>>>(bsums, nb);
  scan3_kernel<<<nb, 256, 0, stream>>>(offs, bsums, N);
  fill_kernel <<<(E + 255) / 256, 256, 0, stream>>>(row, col, offs, cursor, rows_sorted, E);

  wsplit_kernel<<<64, 256, 0, stream>>>(W1,              W1hi,   W1lo);
  wsplit_kernel<<<64, 256, 0, stream>>>(W2,              W2hi,   W2lo);
  wsplit_kernel<<<64, 256, 0, stream>>>(Wm1,             Wm1ahi, Wm1alo);
  wsplit_kernel<<<64, 256, 0, stream>>>(Wm1 + 128 * 128, Wm1bhi, Wm1blo);

  int gemm_grid = (N + 127) / 128;
  int agg_grid  = (N + 3) / 4;

  // conv1: s1 = fp16(dinv * (x@W1));  h1 = relu(dinv*(s1[c] + sum s1[r]) + b1)
  gemm_mfma<<<gemm_grid, 256, 0, stream>>>(x, W1hi, W1lo, dinv, sA, N, 1);
  agg_kernel<<<agg_grid, 256, 0, stream>>>((const __half2*)sA, dinv, offs, counts, rows_sorted, b1, hbuf, N, 1);
  // conv2: s2 = fp16(dinv * (h1@W2)); h2 = dinv*(s2[c] + sum s2[r]) + b2
  gemm_mfma<<<gemm_grid, 256, 0, stream>>>(hbuf, W2hi, W2lo, dinv, sB, N, 1);
  agg_kernel<<<agg_grid, 256, 0, stream>>>((const __half2*)sB, dinv, offs, counts, rows_sorted, b2, hbuf, N, 0);
  // pair head precompute: A = h2 @ Wm1[:128], B = h2 @ Wm1[128:]  (fp16)
  gemm_mfma<<<gemm_grid, 256, 0, stream>>>(hbuf, Wm1ahi, Wm1alo, dinv, sA, N, 0);
  gemm_mfma<<<gemm_grid, 256, 0, stream>>>(hbuf, Wm1bhi, Wm1blo, dinv, sB, N, 0);
  // out[p] = relu(A[src]+B[dst]+bm1) @ Wm2 + bm2
  pair_kernel<<<8192, 256, 0, stream>>>((const __half2*)sA, (const __half2*)sB, psrc, pdst, bm1, Wm2, bm2, outp, P);
}